// Round 9
// baseline (303.610 us; speedup 1.0000x reference)
//
#include <hip/hip_runtime.h>

// ---------------------------------------------------------------------------
// Fused causal MHA: LN -> QKV -> flash attention (S^T trick) -> out proj.
// bf16 MFMA path. B=4, S=2048, D=1024, H=16, hd=64.
// ---------------------------------------------------------------------------

typedef short short8 __attribute__((ext_vector_type(8)));      // 8 bf16 (A/B frag)
typedef float floatx4 __attribute__((ext_vector_type(4)));     // C/D frag
typedef unsigned short ushort4v __attribute__((ext_vector_type(4)));
typedef unsigned int uint2v __attribute__((ext_vector_type(2)));

#define MFMA16(a, b, c) __builtin_amdgcn_mfma_f32_16x16x32_bf16((a), (b), (c), 0, 0, 0)

__device__ __forceinline__ unsigned short f2bf(float f) {
  unsigned int u = __float_as_uint(f);
  u += 0x7FFFu + ((u >> 16) & 1u);
  return (unsigned short)(u >> 16);
}

#if defined(__has_builtin)
#if __has_builtin(__builtin_amdgcn_cvt_pk_bf16_f32)
#define HAVE_PK_BF16 1
#endif
#endif

__device__ __forceinline__ unsigned int pk_bf16(float a, float b) {
#ifdef HAVE_PK_BF16
  typedef __bf16 bf16x2_t __attribute__((ext_vector_type(2)));
  union { bf16x2_t v; unsigned int u; } cvt;
  cvt.v = __builtin_amdgcn_cvt_pk_bf16_f32(a, b);
  return cvt.u;
#else
  return (unsigned int)f2bf(a) | ((unsigned int)f2bf(b) << 16);
#endif
}

// async global -> LDS, 16B per lane. LDS dest = wave-uniform base + lane*16.
__device__ __forceinline__ void async_lds16(const void* g, void* l) {
  __builtin_amdgcn_global_load_lds(
      (const __attribute__((address_space(1))) void*)g,
      (__attribute__((address_space(3))) void*)l, 16, 0, 0);
}

// ---------------------------------------------------------------------------
// Weight transpose + fp32->bf16 cast -> B^T layout [N][K].
// ---------------------------------------------------------------------------
__global__ __launch_bounds__(256) void transpose_w(
    const float* __restrict__ wq, const float* __restrict__ wk,
    const float* __restrict__ wv, const float* __restrict__ wo,
    unsigned short* __restrict__ wqkvT, unsigned short* __restrict__ woT) {
  __shared__ float t[64][65];
  const int r = threadIdx.x >> 6, c = threadIdx.x & 63;
  const int n0 = blockIdx.x * 64, k0 = blockIdx.y * 64, mz = blockIdx.z;
  const float* src = (mz == 0) ? wq : (mz == 1) ? wk : (mz == 2) ? wv : wo;
  unsigned short* dst = (mz == 3) ? woT : (wqkvT + (size_t)mz * 1024 * 1024);
#pragma unroll
  for (int i = r; i < 64; i += 4) t[i][c] = src[(size_t)(k0 + i) * 1024 + n0 + c];
  __syncthreads();
#pragma unroll
  for (int i = r; i < 64; i += 4) dst[(size_t)(n0 + i) * 1024 + k0 + c] = f2bf(t[c][i]);
}

// ---------------------------------------------------------------------------
// LayerNorm: one 256-thread block per row of 1024. fp32 stats, bf16 output.
// ---------------------------------------------------------------------------
__global__ __launch_bounds__(256) void ln_kernel(
    const float* __restrict__ x, const float* __restrict__ gamma,
    const float* __restrict__ beta, unsigned short* __restrict__ h) {
  const int row = blockIdx.x, tid = threadIdx.x;
  const float4 xv = ((const float4*)(x + (size_t)row * 1024))[tid];
  float s = xv.x + xv.y + xv.z + xv.w;
  float q = xv.x * xv.x + xv.y * xv.y + xv.z * xv.z + xv.w * xv.w;
#pragma unroll
  for (int off = 32; off > 0; off >>= 1) {
    s += __shfl_xor(s, off, 64);
    q += __shfl_xor(q, off, 64);
  }
  __shared__ float sm[4], qm[4];
  const int wave = tid >> 6, lane = tid & 63;
  if (lane == 0) { sm[wave] = s; qm[wave] = q; }
  __syncthreads();
  s = sm[0] + sm[1] + sm[2] + sm[3];
  q = qm[0] + qm[1] + qm[2] + qm[3];
  const float mean = s * (1.0f / 1024.0f);
  const float var = q * (1.0f / 1024.0f) - mean * mean;
  const float rstd = rsqrtf(var + 1e-5f);
  const float4 g = ((const float4*)gamma)[tid];
  const float4 bb = ((const float4*)beta)[tid];
  ushort4v o;
  o.x = f2bf((xv.x - mean) * rstd * g.x + bb.x);
  o.y = f2bf((xv.y - mean) * rstd * g.y + bb.y);
  o.z = f2bf((xv.z - mean) * rstd * g.z + bb.z);
  o.w = f2bf((xv.w - mean) * rstd * g.w + bb.w);
  ((ushort4v*)(h + (size_t)row * 1024))[tid] = o;
}

// ---------------------------------------------------------------------------
// m97-style 128x128 GEMM main loop (m0/n0 supplied by caller for swizzling).
// ---------------------------------------------------------------------------
#define GEMM128_MAIN(A_, Bt_, m0_, n0_)                                         \
  __shared__ __align__(16) unsigned short lA[128 * 32];                         \
  __shared__ __align__(16) unsigned short lB[128 * 32];                         \
  const int tid = threadIdx.x;                                                  \
  const int wave = tid >> 6, lane = tid & 63, quad = lane >> 4, l15 = lane & 15;\
  const int wm = wave >> 1, wn = wave & 1;                                      \
  const int m0 = (m0_), n0 = (n0_);                                             \
  const int srow = tid >> 2, schunk = tid & 3;                                  \
  floatx4 acc[4][4];                                                            \
  _Pragma("unroll") for (int i = 0; i < 4; i++)                                 \
  _Pragma("unroll") for (int j = 0; j < 4; j++)                                 \
      acc[i][j] = (floatx4){0.f, 0.f, 0.f, 0.f};                                \
  for (int kt = 0; kt < 32; kt++) {                                             \
    const int k0 = kt * 32;                                                     \
    __syncthreads();                                                            \
    _Pragma("unroll") for (int j = 0; j < 2; j++) {                             \
      async_lds16(A_ + (size_t)(m0 + j * 64 + srow) * 1024 + k0 + schunk * 8,   \
                  (char*)lA + j * 4096 + wave * 1024);                          \
      async_lds16(Bt_ + (size_t)(n0 + j * 64 + srow) * 1024 + k0 + schunk * 8,  \
                  (char*)lB + j * 4096 + wave * 1024);                          \
    }                                                                           \
    __syncthreads();                                                            \
    short8 af[4], bf[4];                                                        \
    _Pragma("unroll") for (int i = 0; i < 4; i++) {                             \
      af[i] = *(const short8*)(lA + (wm * 64 + i * 16 + l15) * 32 + quad * 8);  \
      bf[i] = *(const short8*)(lB + (wn * 64 + i * 16 + l15) * 32 + quad * 8);  \
    }                                                                           \
    _Pragma("unroll") for (int mt = 0; mt < 4; mt++)                            \
    _Pragma("unroll") for (int nt = 0; nt < 4; nt++)                            \
        acc[mt][nt] = MFMA16(af[mt], bf[nt], acc[mt][nt]);                      \
  }

// QKV: M=8192, N=3072. R9: q AND v stored TRANSPOSED [b,h,64,s] (packed 8B
// stores, 4 consecutive s per lane) — only k keeps the [b,h,s,64] layout
// (it must: attn DMA-stages K rows as A-fragments). q PRE-SCALED by
// 0.125*log2(e). 1D grid 1536, XCD n-stripe swizzle.
__global__ __launch_bounds__(256) void gemm_qkv(
    const unsigned short* __restrict__ A, const unsigned short* __restrict__ Bt,
    const float* __restrict__ bq, const float* __restrict__ bk,
    const float* __restrict__ bv, unsigned short* __restrict__ qT,
    unsigned short* __restrict__ ko, unsigned short* __restrict__ vT) {
  const int id = (int)blockIdx.x;
  const int xcd = id & 7, rr = id >> 3;
  GEMM128_MAIN(A, Bt, (rr / 3) * 128, (xcd * 3 + (rr % 3)) * 128)
  const int sel = n0 >> 10;  // uniform per block
  const float* bias = (sel == 0) ? bq : (sel == 1) ? bk : bv;
  const float oscale = (sel == 0) ? 0.18033688011112042f : 1.0f;  // 1/8 * log2(e)
#pragma unroll
  for (int nt = 0; nt < 4; nt++) {
    const int n = n0 + wn * 64 + nt * 16 + l15;
    const int nn = n & 1023;
    const float bia = bias[nn];
    const int hidx = nn >> 6, d = nn & 63;
#pragma unroll
    for (int mt = 0; mt < 4; mt++) {
      const int mb = m0 + wm * 64 + mt * 16 + quad * 4;
      const int b = mb >> 11, sdx = mb & 2047;
      if (sel != 1) {
        // q (scaled) and v: transposed [b,h,64,s], packed 8B stores
        unsigned short* dstT = (sel == 0) ? qT : vT;
        ushort4v pk;
#pragma unroll
        for (int r = 0; r < 4; r++) pk[r] = f2bf((acc[mt][nt][r] + bia) * oscale);
        *(ushort4v*)(dstT + ((size_t)(b * 16 + hidx) * 64 + d) * 2048 + sdx) = pk;
      } else {
        unsigned short* dst = ko + ((size_t)(b * 16 + hidx) * 2048 + sdx) * 64 + d;
#pragma unroll
        for (int r = 0; r < 4; r++) dst[(size_t)r * 64] = f2bf(acc[mt][nt][r] + bia);
      }
    }
  }
}

// Out proj: M=8192, N=1024, fp32 output + bias. 1D grid 512, one n-tile/XCD.
__global__ __launch_bounds__(256) void gemm_out(
    const unsigned short* __restrict__ A, const unsigned short* __restrict__ Bt,
    const float* __restrict__ bo, float* __restrict__ out) {
  const int id = (int)blockIdx.x;
  GEMM128_MAIN(A, Bt, (id >> 3) * 128, (id & 7) * 128)
#pragma unroll
  for (int nt = 0; nt < 4; nt++) {
    const int n = n0 + wn * 64 + nt * 16 + l15;
    const float bia = bo[n];
#pragma unroll
    for (int mt = 0; mt < 4; mt++) {
      const int m = m0 + wm * 64 + mt * 16 + quad * 4;
#pragma unroll
      for (int r = 0; r < 4; r++) out[(size_t)(m + r) * 1024 + n] = acc[mt][nt][r] + bia;
    }
  }
}

// ---------------------------------------------------------------------------
// Flash attention, causal, S^T formulation. R9 = R8 structure; only change:
// Q is now in transposed layout [b,h,64,s], so Q B-frags are gathered with
// 16 scalar 2B loads per set (once per block lifetime — amortized over the
// whole K sweep; all L2-hits via XCD locality).
//  - V in LDS (per-wave global V = 4x L2 amplification, R7 lesson).
//  - MERGED PASSES: one sweep over 32-qx key-tiles serves q-tiles (31-qx, qx);
//    K/V LDS reads shared by both q-sets on dual tiles; 18*33 MFMA/block.
//  - NO-MAX softmax (log2-domain scores), denominator via ones-MFMA.
//  - XCD-locality decode; LDS 40 KB; launch_bounds(256,4).
// ---------------------------------------------------------------------------
__global__ __launch_bounds__(256, 4) void attn_kernel(
    const unsigned short* __restrict__ qT, const unsigned short* __restrict__ k,
    const unsigned short* __restrict__ vT, unsigned short* __restrict__ ao) {
  __shared__ __align__(16) unsigned short lK[2][64 * 64];  // 16 KB dbuf
  __shared__ __align__(16) unsigned short lV[2][64 * 64];  // 16 KB dbuf
  __shared__ __align__(16) unsigned short lP[4][16 * 64];  // 8 KB (swizzled)
  const int tid = threadIdx.x;
  const int wave = tid >> 6, lane = tid & 63, quad = lane >> 4, l15 = lane & 15;
  // XCD-aware decode: id&7 = XCD (dispatch round-robin); 8 bh per XCD.
  const int id = (int)blockIdx.x;
  const int bh = (id & 7) * 8 + ((id >> 3) & 7);
  const int qx = id >> 6;  // 0..15
  const int b = bh >> 4, hh = bh & 15;
  const int qtA = 31 - qx, qtB = qx;  // big & small q-tiles, qtB < qtA
  const int q0wA = qtA * 64 + wave * 16, q0wB = qtB * 64 + wave * 16;
  const int ntiles = qtA + 1;

  const unsigned short* qb = qT + (size_t)bh * 64 * 2048;  // [d][s]
  const unsigned short* kb = k + (size_t)bh * 2048 * 64;   // [s][d]
  const unsigned short* vb = vT + (size_t)bh * 64 * 2048;  // [d][s]
  unsigned short* pw = &lP[wave][0];

  const int srow = tid >> 3, schunk = tid & 7;  // staging row / 16B chunk

  // all-ones bf16 A-fragment for the denominator MFMA
  const short8 ones8 = {0x3F80, 0x3F80, 0x3F80, 0x3F80,
                        0x3F80, 0x3F80, 0x3F80, 0x3F80};

  // loop-invariant un-swizzle chunk indices (row&7 == l15&7 for all nt)
  const int sw = l15 & 7;
  const int ph0 = (0 * 4 + quad) ^ sw, ph1 = (1 * 4 + quad) ^ sw;

  // stage 64x64 bf16 tile, rows at rstride_, cols [cbase_, cbase_+64):
  // 16B chunk XOR-swizzled by (row&7) to kill read bank conflicts
#define STAGE_TILE(src_, rstride_, cbase_, dst_)                                 \
  _Pragma("unroll") for (int j = 0; j < 2; j++) {                                \
    const int row_ = j * 32 + srow;                                              \
    const int gch_ = schunk ^ (row_ & 7);                                        \
    async_lds16(src_ + (size_t)row_ * (rstride_) + (cbase_) + gch_ * 8,          \
                (char*)(dst_) + j * 4096 + wave * 1024);                         \
  }

  // Q B-frags (n = query = lane's l15 column, k-dim = hf*32 + quad*8 + j),
  // gathered from transposed layout qT[d][s] with scalar loads (once/block).
  short8 qfA[2], qfB[2];
#pragma unroll
  for (int hf = 0; hf < 2; hf++) {
#pragma unroll
    for (int j = 0; j < 8; j++) {
      const size_t drow = (size_t)(hf * 32 + quad * 8 + j) * 2048;
      ((unsigned short*)&qfA[hf])[j] = qb[drow + q0wA + l15];
      ((unsigned short*)&qfB[hf])[j] = qb[drow + q0wB + l15];
    }
  }

  floatx4 oA[4], oB[4];
#pragma unroll
  for (int nt = 0; nt < 4; nt++) {
    oA[nt] = (floatx4){0.f, 0.f, 0.f, 0.f};
    oB[nt] = (floatx4){0.f, 0.f, 0.f, 0.f};
  }
  floatx4 laccA = {0.f, 0.f, 0.f, 0.f}, laccB = {0.f, 0.f, 0.f, 0.f};

  STAGE_TILE(kb, 64, 0, &lK[0][0])
  STAGE_TILE(vb, 2048, 0, &lV[0][0])
  int kbase = 0;
  for (int t = 0; t < ntiles; t++, kbase += 64) {
    __syncthreads();  // tile t staged & visible to all waves
    if (t + 1 < ntiles) {
      const int nb = (t + 1) & 1;
      STAGE_TILE(kb, 64, (size_t)(kbase + 64) * 64, &lK[nb][0])
      STAGE_TILE(vb, 2048, (size_t)(kbase + 64), &lV[nb][0])
    }
    const unsigned short* lKc = &lK[t & 1][0];
    const unsigned short* lVc = &lV[t & 1][0];
    const bool dual = (t <= qtB);  // block-uniform

    // S^T = K·Q^T for both q-sets, sharing the K fragments
    floatx4 scA[4], scB[4];
#pragma unroll
    for (int nt = 0; nt < 4; nt++) {
      scA[nt] = (floatx4){0.f, 0.f, 0.f, 0.f};
      scB[nt] = (floatx4){0.f, 0.f, 0.f, 0.f};
      const short8 kf0 = *(const short8*)(lKc + (nt * 16 + l15) * 64 + ph0 * 8);
      const short8 kf1 = *(const short8*)(lKc + (nt * 16 + l15) * 64 + ph1 * 8);
      scA[nt] = MFMA16(kf0, qfA[0], scA[nt]);
      scA[nt] = MFMA16(kf1, qfA[1], scA[nt]);
      if (dual) {
        scB[nt] = MFMA16(kf0, qfB[0], scB[nt]);
        scB[nt] = MFMA16(kf1, qfB[1], scB[nt]);
      }
    }

    // softmax A -> P buffer (no-max: p = exp2(s); mask only boundary tiles)
    {
      const bool needmask = (kbase + 63 > q0wA);
      const int qg = q0wA + l15;
#pragma unroll
      for (int nt = 0; nt < 4; nt++) {
        float p0 = exp2f(scA[nt][0]), p1 = exp2f(scA[nt][1]);
        float p2 = exp2f(scA[nt][2]), p3 = exp2f(scA[nt][3]);
        if (needmask) {
          const int kk = kbase + nt * 16 + quad * 4;
          if (kk + 0 > qg) p0 = 0.f;
          if (kk + 1 > qg) p1 = 0.f;
          if (kk + 2 > qg) p2 = 0.f;
          if (kk + 3 > qg) p3 = 0.f;
        }
        uint2v pk2;
        pk2.x = pk_bf16(p0, p1);
        pk2.y = pk_bf16(p2, p3);
        const int phys = (nt * 2 + (quad >> 1)) ^ sw;
        *(uint2v*)(pw + l15 * 64 + phys * 8 + (quad & 1) * 4) = pk2;
      }
    }
    asm volatile("s_waitcnt lgkmcnt(0)" ::: "memory");  // P_A visible
    short8 pfA0 = *(const short8*)(pw + l15 * 64 + ph0 * 8);
    short8 pfA1 = *(const short8*)(pw + l15 * 64 + ph1 * 8);

    short8 pfB0, pfB1;
    if (dual) {
      // softmax B overwrites the same P buffer; same-wave DS in-order makes
      // the writes safe w.r.t. the pfA reads above.
      const bool needmask = (kbase + 63 > q0wB);
      const int qg = q0wB + l15;
#pragma unroll
      for (int nt = 0; nt < 4; nt++) {
        float p0 = exp2f(scB[nt][0]), p1 = exp2f(scB[nt][1]);
        float p2 = exp2f(scB[nt][2]), p3 = exp2f(scB[nt][3]);
        if (needmask) {
          const int kk = kbase + nt * 16 + quad * 4;
          if (kk + 0 > qg) p0 = 0.f;
          if (kk + 1 > qg) p1 = 0.f;
          if (kk + 2 > qg) p2 = 0.f;
          if (kk + 3 > qg) p3 = 0.f;
        }
        uint2v pk2;
        pk2.x = pk_bf16(p0, p1);
        pk2.y = pk_bf16(p2, p3);
        const int phys = (nt * 2 + (quad >> 1)) ^ sw;
        *(uint2v*)(pw + l15 * 64 + phys * 8 + (quad & 1) * 4) = pk2;
      }
      asm volatile("s_waitcnt lgkmcnt(0)" ::: "memory");  // pfA in regs, P_B visible
      pfB0 = *(const short8*)(pw + l15 * 64 + ph0 * 8);
      pfB1 = *(const short8*)(pw + l15 * 64 + ph1 * 8);
    }

    // PV for both q-sets sharing the V fragments
#pragma unroll
    for (int hf = 0; hf < 2; hf++) {
      const short8 pfA = hf ? pfA1 : pfA0;
      laccA = MFMA16(ones8, pfA, laccA);
      if (dual) laccB = MFMA16(ones8, hf ? pfB1 : pfB0, laccB);
      const int ph = hf ? ph1 : ph0;
#pragma unroll
      for (int nt = 0; nt < 4; nt++) {
        const short8 vf = *(const short8*)(lVc + (nt * 16 + l15) * 64 + ph * 8);
        oA[nt] = MFMA16(vf, pfA, oA[nt]);
        if (dual) oB[nt] = MFMA16(vf, hf ? pfB1 : pfB0, oB[nt]);
      }
    }
  }

  // epilogue: normalize (per-lane; lacc rows all equal) + packed 8B stores
  {
    const float linv = 1.0f / laccA[0];
    unsigned short* dst = ao + ((size_t)b * 2048 + q0wA + l15) * 1024 + hh * 64;
#pragma unroll
    for (int nt = 0; nt < 4; nt++) {
      uint2v pk2;
      pk2.x = pk_bf16(oA[nt][0] * linv, oA[nt][1] * linv);
      pk2.y = pk_bf16(oA[nt][2] * linv, oA[nt][3] * linv);
      *(uint2v*)(dst + nt * 16 + quad * 4) = pk2;
    }
  }
  {
    const float linv = 1.0f / laccB[0];
    unsigned short* dst = ao + ((size_t)b * 2048 + q0wB + l15) * 1024 + hh * 64;
#pragma unroll
    for (int nt = 0; nt < 4; nt++) {
      uint2v pk2;
      pk2.x = pk_bf16(oB[nt][0] * linv, oB[nt][1] * linv);
      pk2.y = pk_bf16(oB[nt][2] * linv, oB[nt][3] * linv);
      *(uint2v*)(dst + nt * 16 + quad * 4) = pk2;
    }
  }
#undef STAGE_TILE
}

// ---------------------------------------------------------------------------
extern "C" void kernel_launch(void* const* d_in, const int* in_sizes, int n_in,
                              void* d_out, int out_size, void* d_ws, size_t ws_size,
                              hipStream_t stream) {
  const float* x = (const float*)d_in[0];
  const float* Wq = (const float*)d_in[1];
  const float* bq = (const float*)d_in[2];
  const float* Wk = (const float*)d_in[3];
  const float* bk = (const float*)d_in[4];
  const float* Wv = (const float*)d_in[5];
  const float* bv = (const float*)d_in[6];
  const float* Wo = (const float*)d_in[7];
  const float* bo = (const float*)d_in[8];
  const float* gamma = (const float*)d_in[9];
  const float* beta = (const float*)d_in[10];
  float* out = (float*)d_out;

  char* ws = (char*)d_ws;
  unsigned short* wqkvT = (unsigned short*)(ws + 0);          // 6 MB
  unsigned short* woT   = (unsigned short*)(ws + 6291456);    // 2 MB
  unsigned short* h     = (unsigned short*)(ws + 8388608);    // 16 MB
  unsigned short* qT    = (unsigned short*)(ws + 25165824);   // [b,h,64,s] 16 MB
  unsigned short* kb    = (unsigned short*)(ws + 41943040);   // [b,h,s,64] 16 MB
  unsigned short* vT    = (unsigned short*)(ws + 58720256);   // [b,h,64,s] 16 MB
  unsigned short* ao    = (unsigned short*)(ws + 75497472);   // [b,s,1024] 16 MB

  hipLaunchKernelGGL(transpose_w, dim3(16, 16, 4), dim3(256), 0, stream,
                     Wq, Wk, Wv, Wo, wqkvT, woT);
  hipLaunchKernelGGL(ln_kernel, dim3(8192), dim3(256), 0, stream, x, gamma, beta, h);
  hipLaunchKernelGGL(gemm_qkv, dim3(1536), dim3(256), 0, stream,
                     h, wqkvT, bq, bk, bv, qT, kb, vT);
  hipLaunchKernelGGL(attn_kernel, dim3(1024), dim3(256), 0, stream, qT, kb, vT, ao);
  hipLaunchKernelGGL(gemm_out, dim3(512), dim3(256), 0, stream, ao, woT, bo, out);
}

// Round 10
// 279.796 us; speedup vs baseline: 1.0851x; 1.0851x over previous
//
#include <hip/hip_runtime.h>

// ---------------------------------------------------------------------------
// Fused causal MHA: LN -> QKV -> flash attention (S^T trick) -> out proj.
// bf16 MFMA path. B=4, S=2048, D=1024, H=16, hd=64.
// ---------------------------------------------------------------------------

typedef short short8 __attribute__((ext_vector_type(8)));      // 8 bf16 (A/B frag)
typedef float floatx4 __attribute__((ext_vector_type(4)));     // C/D frag
typedef unsigned short ushort4v __attribute__((ext_vector_type(4)));
typedef unsigned int uint2v __attribute__((ext_vector_type(2)));

#define MFMA16(a, b, c) __builtin_amdgcn_mfma_f32_16x16x32_bf16((a), (b), (c), 0, 0, 0)

__device__ __forceinline__ unsigned short f2bf(float f) {
  unsigned int u = __float_as_uint(f);
  u += 0x7FFFu + ((u >> 16) & 1u);
  return (unsigned short)(u >> 16);
}

#if defined(__has_builtin)
#if __has_builtin(__builtin_amdgcn_cvt_pk_bf16_f32)
#define HAVE_PK_BF16 1
#endif
#if __has_builtin(__builtin_amdgcn_exp2f)
#define EXP2(x) __builtin_amdgcn_exp2f(x)
#endif
#if __has_builtin(__builtin_amdgcn_rcpf)
#define RCP(x) __builtin_amdgcn_rcpf(x)
#endif
#endif
#ifndef EXP2
#define EXP2(x) exp2f(x)
#endif
#ifndef RCP
#define RCP(x) (1.0f / (x))
#endif

__device__ __forceinline__ unsigned int pk_bf16(float a, float b) {
#ifdef HAVE_PK_BF16
  typedef __bf16 bf16x2_t __attribute__((ext_vector_type(2)));
  union { bf16x2_t v; unsigned int u; } cvt;
  cvt.v = __builtin_amdgcn_cvt_pk_bf16_f32(a, b);
  return cvt.u;
#else
  return (unsigned int)f2bf(a) | ((unsigned int)f2bf(b) << 16);
#endif
}

// async global -> LDS, 16B per lane. LDS dest = wave-uniform base + lane*16.
__device__ __forceinline__ void async_lds16(const void* g, void* l) {
  __builtin_amdgcn_global_load_lds(
      (const __attribute__((address_space(1))) void*)g,
      (__attribute__((address_space(3))) void*)l, 16, 0, 0);
}

// ---------------------------------------------------------------------------
// Fused prep: blocks [0,1024) transpose weights fp32->bf16 into B^T layout;
// blocks [1024, 9216) do LayerNorm (one block per row). Saves a launch gap.
// ---------------------------------------------------------------------------
__global__ __launch_bounds__(256) void prep_kernel(
    const float* __restrict__ wq, const float* __restrict__ wk,
    const float* __restrict__ wv, const float* __restrict__ wo,
    unsigned short* __restrict__ wqkvT, unsigned short* __restrict__ woT,
    const float* __restrict__ x, const float* __restrict__ gamma,
    const float* __restrict__ beta, unsigned short* __restrict__ h) {
  __shared__ float t[64][65];
  __shared__ float sm[4], qm[4];
  const int id = (int)blockIdx.x;
  const int tid = threadIdx.x;
  if (id < 1024) {
    // ---- weight transpose ----
    const int mz = id >> 8, rem = id & 255;
    const int n0 = (rem & 15) * 64, k0 = (rem >> 4) * 64;
    const int r = tid >> 6, c = tid & 63;
    const float* src = (mz == 0) ? wq : (mz == 1) ? wk : (mz == 2) ? wv : wo;
    unsigned short* dst = (mz == 3) ? woT : (wqkvT + (size_t)mz * 1024 * 1024);
#pragma unroll
    for (int i = r; i < 64; i += 4) t[i][c] = src[(size_t)(k0 + i) * 1024 + n0 + c];
    __syncthreads();
#pragma unroll
    for (int i = r; i < 64; i += 4)
      dst[(size_t)(n0 + i) * 1024 + k0 + c] = f2bf(t[c][i]);
    return;
  }
  // ---- LayerNorm ----
  const int row = id - 1024;
  const float4 xv = ((const float4*)(x + (size_t)row * 1024))[tid];
  float s = xv.x + xv.y + xv.z + xv.w;
  float q = xv.x * xv.x + xv.y * xv.y + xv.z * xv.z + xv.w * xv.w;
#pragma unroll
  for (int off = 32; off > 0; off >>= 1) {
    s += __shfl_xor(s, off, 64);
    q += __shfl_xor(q, off, 64);
  }
  const int wave = tid >> 6, lane = tid & 63;
  if (lane == 0) { sm[wave] = s; qm[wave] = q; }
  __syncthreads();
  s = sm[0] + sm[1] + sm[2] + sm[3];
  q = qm[0] + qm[1] + qm[2] + qm[3];
  const float mean = s * (1.0f / 1024.0f);
  const float var = q * (1.0f / 1024.0f) - mean * mean;
  const float rstd = rsqrtf(var + 1e-5f);
  const float4 g = ((const float4*)gamma)[tid];
  const float4 bb = ((const float4*)beta)[tid];
  ushort4v o;
  o.x = f2bf((xv.x - mean) * rstd * g.x + bb.x);
  o.y = f2bf((xv.y - mean) * rstd * g.y + bb.y);
  o.z = f2bf((xv.z - mean) * rstd * g.z + bb.z);
  o.w = f2bf((xv.w - mean) * rstd * g.w + bb.w);
  ((ushort4v*)(h + (size_t)row * 1024))[tid] = o;
}

// ---------------------------------------------------------------------------
// m97-style 128x128 GEMM main loop (m0/n0 supplied by caller for swizzling).
// ---------------------------------------------------------------------------
#define GEMM128_MAIN(A_, Bt_, m0_, n0_)                                         \
  __shared__ __align__(16) unsigned short lA[128 * 32];                         \
  __shared__ __align__(16) unsigned short lB[128 * 32];                         \
  const int tid = threadIdx.x;                                                  \
  const int wave = tid >> 6, lane = tid & 63, quad = lane >> 4, l15 = lane & 15;\
  const int wm = wave >> 1, wn = wave & 1;                                      \
  const int m0 = (m0_), n0 = (n0_);                                             \
  const int srow = tid >> 2, schunk = tid & 3;                                  \
  floatx4 acc[4][4];                                                            \
  _Pragma("unroll") for (int i = 0; i < 4; i++)                                 \
  _Pragma("unroll") for (int j = 0; j < 4; j++)                                 \
      acc[i][j] = (floatx4){0.f, 0.f, 0.f, 0.f};                                \
  for (int kt = 0; kt < 32; kt++) {                                             \
    const int k0 = kt * 32;                                                     \
    __syncthreads();                                                            \
    _Pragma("unroll") for (int j = 0; j < 2; j++) {                             \
      async_lds16(A_ + (size_t)(m0 + j * 64 + srow) * 1024 + k0 + schunk * 8,   \
                  (char*)lA + j * 4096 + wave * 1024);                          \
      async_lds16(Bt_ + (size_t)(n0 + j * 64 + srow) * 1024 + k0 + schunk * 8,  \
                  (char*)lB + j * 4096 + wave * 1024);                          \
    }                                                                           \
    __syncthreads();                                                            \
    short8 af[4], bf[4];                                                        \
    _Pragma("unroll") for (int i = 0; i < 4; i++) {                             \
      af[i] = *(const short8*)(lA + (wm * 64 + i * 16 + l15) * 32 + quad * 8);  \
      bf[i] = *(const short8*)(lB + (wn * 64 + i * 16 + l15) * 32 + quad * 8);  \
    }                                                                           \
    _Pragma("unroll") for (int mt = 0; mt < 4; mt++)                            \
    _Pragma("unroll") for (int nt = 0; nt < 4; nt++)                            \
        acc[mt][nt] = MFMA16(af[mt], bf[nt], acc[mt][nt]);                      \
  }

// QKV: M=8192, N=3072. q,k -> [b,h,s,64]; v -> [b,h,64,s] (R8 layout).
// q PRE-SCALED by 0.125*log2(e). 1D grid 1536, XCD n-stripe swizzle.
__global__ __launch_bounds__(256) void gemm_qkv(
    const unsigned short* __restrict__ A, const unsigned short* __restrict__ Bt,
    const float* __restrict__ bq, const float* __restrict__ bk,
    const float* __restrict__ bv, unsigned short* __restrict__ qo,
    unsigned short* __restrict__ ko, unsigned short* __restrict__ vT) {
  const int id = (int)blockIdx.x;
  const int xcd = id & 7, rr = id >> 3;
  GEMM128_MAIN(A, Bt, (rr / 3) * 128, (xcd * 3 + (rr % 3)) * 128)
  const int sel = n0 >> 10;  // uniform per block
  const float* bias = (sel == 0) ? bq : (sel == 1) ? bk : bv;
  const float oscale = (sel == 0) ? 0.18033688011112042f : 1.0f;  // 1/8 * log2(e)
#pragma unroll
  for (int nt = 0; nt < 4; nt++) {
    const int n = n0 + wn * 64 + nt * 16 + l15;
    const int nn = n & 1023;
    const float bia = bias[nn];
    const int hidx = nn >> 6, d = nn & 63;
#pragma unroll
    for (int mt = 0; mt < 4; mt++) {
      const int mb = m0 + wm * 64 + mt * 16 + quad * 4;
      const int b = mb >> 11, sdx = mb & 2047;
      if (sel == 2) {
        ushort4v pk;
#pragma unroll
        for (int r = 0; r < 4; r++) pk[r] = f2bf(acc[mt][nt][r] + bia);
        *(ushort4v*)(vT + ((size_t)(b * 16 + hidx) * 64 + d) * 2048 + sdx) = pk;
      } else {
        unsigned short* dst =
            ((sel == 0) ? qo : ko) + ((size_t)(b * 16 + hidx) * 2048 + sdx) * 64 + d;
#pragma unroll
        for (int r = 0; r < 4; r++)
          dst[(size_t)r * 64] = f2bf((acc[mt][nt][r] + bia) * oscale);
      }
    }
  }
}

// Out proj: M=8192, N=1024, fp32 output + bias. 1D grid 512, one n-tile/XCD.
__global__ __launch_bounds__(256) void gemm_out(
    const unsigned short* __restrict__ A, const unsigned short* __restrict__ Bt,
    const float* __restrict__ bo, float* __restrict__ out) {
  const int id = (int)blockIdx.x;
  GEMM128_MAIN(A, Bt, (id >> 3) * 128, (id & 7) * 128)
#pragma unroll
  for (int nt = 0; nt < 4; nt++) {
    const int n = n0 + wn * 64 + nt * 16 + l15;
    const float bia = bo[n];
#pragma unroll
    for (int mt = 0; mt < 4; mt++) {
      const int m = m0 + wm * 64 + mt * 16 + quad * 4;
#pragma unroll
      for (int r = 0; r < 4; r++) out[(size_t)(m + r) * 1024 + n] = acc[mt][nt][r] + bia;
    }
  }
}

// ---------------------------------------------------------------------------
// Flash attention, causal, S^T formulation. R10 = R8 structure with native
// math: raw v_exp_f32 (__builtin_amdgcn_exp2f) instead of OCML exp2f (which
// expands to ~6-8 VALU ops for denormal/range handling), and v_rcp_f32 for
// the normalizer. Everything else identical to R8 (the 299 us config):
//  - V in LDS (per-wave global V = 4x L2 amplification, R7 lesson).
//  - MERGED PASSES: one sweep over 32-qx key-tiles serves q-tiles (31-qx, qx).
//  - NO-MAX softmax (log2-domain scores), denominator via ones-MFMA.
//  - XCD-locality decode; LDS 40 KB; launch_bounds(256,4).
// ---------------------------------------------------------------------------
__global__ __launch_bounds__(256, 4) void attn_kernel(
    const unsigned short* __restrict__ q, const unsigned short* __restrict__ k,
    const unsigned short* __restrict__ vT, unsigned short* __restrict__ ao) {
  __shared__ __align__(16) unsigned short lK[2][64 * 64];  // 16 KB dbuf
  __shared__ __align__(16) unsigned short lV[2][64 * 64];  // 16 KB dbuf
  __shared__ __align__(16) unsigned short lP[4][16 * 64];  // 8 KB (swizzled)
  const int tid = threadIdx.x;
  const int wave = tid >> 6, lane = tid & 63, quad = lane >> 4, l15 = lane & 15;
  // XCD-aware decode: id&7 = XCD (dispatch round-robin); 8 bh per XCD.
  const int id = (int)blockIdx.x;
  const int bh = (id & 7) * 8 + ((id >> 3) & 7);
  const int qx = id >> 6;  // 0..15
  const int b = bh >> 4, hh = bh & 15;
  const int qtA = 31 - qx, qtB = qx;  // big & small q-tiles, qtB < qtA
  const int q0wA = qtA * 64 + wave * 16, q0wB = qtB * 64 + wave * 16;
  const int ntiles = qtA + 1;

  const unsigned short* qb = q + (size_t)bh * 2048 * 64;
  const unsigned short* kb = k + (size_t)bh * 2048 * 64;
  const unsigned short* vb = vT + (size_t)bh * 64 * 2048;
  unsigned short* pw = &lP[wave][0];

  const int srow = tid >> 3, schunk = tid & 7;  // staging row / 16B chunk

  // all-ones bf16 A-fragment for the denominator MFMA
  const short8 ones8 = {0x3F80, 0x3F80, 0x3F80, 0x3F80,
                        0x3F80, 0x3F80, 0x3F80, 0x3F80};

  // loop-invariant un-swizzle chunk indices (row&7 == l15&7 for all nt)
  const int sw = l15 & 7;
  const int ph0 = (0 * 4 + quad) ^ sw, ph1 = (1 * 4 + quad) ^ sw;

  // stage 64x64 bf16 tile, rows at rstride_, cols [cbase_, cbase_+64):
  // 16B chunk XOR-swizzled by (row&7) to kill read bank conflicts
#define STAGE_TILE(src_, rstride_, cbase_, dst_)                                 \
  _Pragma("unroll") for (int j = 0; j < 2; j++) {                                \
    const int row_ = j * 32 + srow;                                              \
    const int gch_ = schunk ^ (row_ & 7);                                        \
    async_lds16(src_ + (size_t)row_ * (rstride_) + (cbase_) + gch_ * 8,          \
                (char*)(dst_) + j * 4096 + wave * 1024);                         \
  }

  // Q B-frags for both q-tiles: n = query, k = hf*32 + quad*8 + j
  short8 qfA[2], qfB[2];
#pragma unroll
  for (int hf = 0; hf < 2; hf++) {
    qfA[hf] = *(const short8*)(qb + (size_t)(q0wA + l15) * 64 + hf * 32 + quad * 8);
    qfB[hf] = *(const short8*)(qb + (size_t)(q0wB + l15) * 64 + hf * 32 + quad * 8);
  }

  floatx4 oA[4], oB[4];
#pragma unroll
  for (int nt = 0; nt < 4; nt++) {
    oA[nt] = (floatx4){0.f, 0.f, 0.f, 0.f};
    oB[nt] = (floatx4){0.f, 0.f, 0.f, 0.f};
  }
  floatx4 laccA = {0.f, 0.f, 0.f, 0.f}, laccB = {0.f, 0.f, 0.f, 0.f};

  STAGE_TILE(kb, 64, 0, &lK[0][0])
  STAGE_TILE(vb, 2048, 0, &lV[0][0])
  int kbase = 0;
  for (int t = 0; t < ntiles; t++, kbase += 64) {
    __syncthreads();  // tile t staged & visible to all waves
    if (t + 1 < ntiles) {
      const int nb = (t + 1) & 1;
      STAGE_TILE(kb, 64, (size_t)(kbase + 64) * 64, &lK[nb][0])
      STAGE_TILE(vb, 2048, (size_t)(kbase + 64), &lV[nb][0])
    }
    const unsigned short* lKc = &lK[t & 1][0];
    const unsigned short* lVc = &lV[t & 1][0];
    const bool dual = (t <= qtB);  // block-uniform

    // S^T = K·Q^T for both q-sets, sharing the K fragments
    floatx4 scA[4], scB[4];
#pragma unroll
    for (int nt = 0; nt < 4; nt++) {
      scA[nt] = (floatx4){0.f, 0.f, 0.f, 0.f};
      scB[nt] = (floatx4){0.f, 0.f, 0.f, 0.f};
      const short8 kf0 = *(const short8*)(lKc + (nt * 16 + l15) * 64 + ph0 * 8);
      const short8 kf1 = *(const short8*)(lKc + (nt * 16 + l15) * 64 + ph1 * 8);
      scA[nt] = MFMA16(kf0, qfA[0], scA[nt]);
      scA[nt] = MFMA16(kf1, qfA[1], scA[nt]);
      if (dual) {
        scB[nt] = MFMA16(kf0, qfB[0], scB[nt]);
        scB[nt] = MFMA16(kf1, qfB[1], scB[nt]);
      }
    }

    // softmax A -> P buffer (no-max: p = exp2(s); mask only boundary tiles)
    {
      const bool needmask = (kbase + 63 > q0wA);
      const int qg = q0wA + l15;
#pragma unroll
      for (int nt = 0; nt < 4; nt++) {
        float p0 = EXP2(scA[nt][0]), p1 = EXP2(scA[nt][1]);
        float p2 = EXP2(scA[nt][2]), p3 = EXP2(scA[nt][3]);
        if (needmask) {
          const int kk = kbase + nt * 16 + quad * 4;
          if (kk + 0 > qg) p0 = 0.f;
          if (kk + 1 > qg) p1 = 0.f;
          if (kk + 2 > qg) p2 = 0.f;
          if (kk + 3 > qg) p3 = 0.f;
        }
        uint2v pk2;
        pk2.x = pk_bf16(p0, p1);
        pk2.y = pk_bf16(p2, p3);
        const int phys = (nt * 2 + (quad >> 1)) ^ sw;
        *(uint2v*)(pw + l15 * 64 + phys * 8 + (quad & 1) * 4) = pk2;
      }
    }
    asm volatile("s_waitcnt lgkmcnt(0)" ::: "memory");  // P_A visible
    short8 pfA0 = *(const short8*)(pw + l15 * 64 + ph0 * 8);
    short8 pfA1 = *(const short8*)(pw + l15 * 64 + ph1 * 8);

    short8 pfB0, pfB1;
    if (dual) {
      // softmax B overwrites the same P buffer; same-wave DS in-order makes
      // the writes safe w.r.t. the pfA reads above.
      const bool needmask = (kbase + 63 > q0wB);
      const int qg = q0wB + l15;
#pragma unroll
      for (int nt = 0; nt < 4; nt++) {
        float p0 = EXP2(scB[nt][0]), p1 = EXP2(scB[nt][1]);
        float p2 = EXP2(scB[nt][2]), p3 = EXP2(scB[nt][3]);
        if (needmask) {
          const int kk = kbase + nt * 16 + quad * 4;
          if (kk + 0 > qg) p0 = 0.f;
          if (kk + 1 > qg) p1 = 0.f;
          if (kk + 2 > qg) p2 = 0.f;
          if (kk + 3 > qg) p3 = 0.f;
        }
        uint2v pk2;
        pk2.x = pk_bf16(p0, p1);
        pk2.y = pk_bf16(p2, p3);
        const int phys = (nt * 2 + (quad >> 1)) ^ sw;
        *(uint2v*)(pw + l15 * 64 + phys * 8 + (quad & 1) * 4) = pk2;
      }
      asm volatile("s_waitcnt lgkmcnt(0)" ::: "memory");  // pfA in regs, P_B visible
      pfB0 = *(const short8*)(pw + l15 * 64 + ph0 * 8);
      pfB1 = *(const short8*)(pw + l15 * 64 + ph1 * 8);
    }

    // PV for both q-sets sharing the V fragments
#pragma unroll
    for (int hf = 0; hf < 2; hf++) {
      const short8 pfA = hf ? pfA1 : pfA0;
      laccA = MFMA16(ones8, pfA, laccA);
      if (dual) laccB = MFMA16(ones8, hf ? pfB1 : pfB0, laccB);
      const int ph = hf ? ph1 : ph0;
#pragma unroll
      for (int nt = 0; nt < 4; nt++) {
        const short8 vf = *(const short8*)(lVc + (nt * 16 + l15) * 64 + ph * 8);
        oA[nt] = MFMA16(vf, pfA, oA[nt]);
        if (dual) oB[nt] = MFMA16(vf, hf ? pfB1 : pfB0, oB[nt]);
      }
    }
  }

  // epilogue: normalize (per-lane; lacc rows all equal) + packed 8B stores
  {
    const float linv = RCP(laccA[0]);
    unsigned short* dst = ao + ((size_t)b * 2048 + q0wA + l15) * 1024 + hh * 64;
#pragma unroll
    for (int nt = 0; nt < 4; nt++) {
      uint2v pk2;
      pk2.x = pk_bf16(oA[nt][0] * linv, oA[nt][1] * linv);
      pk2.y = pk_bf16(oA[nt][2] * linv, oA[nt][3] * linv);
      *(uint2v*)(dst + nt * 16 + quad * 4) = pk2;
    }
  }
  {
    const float linv = RCP(laccB[0]);
    unsigned short* dst = ao + ((size_t)b * 2048 + q0wB + l15) * 1024 + hh * 64;
#pragma unroll
    for (int nt = 0; nt < 4; nt++) {
      uint2v pk2;
      pk2.x = pk_bf16(oB[nt][0] * linv, oB[nt][1] * linv);
      pk2.y = pk_bf16(oB[nt][2] * linv, oB[nt][3] * linv);
      *(uint2v*)(dst + nt * 16 + quad * 4) = pk2;
    }
  }
#undef STAGE_TILE
}

// ---------------------------------------------------------------------------
extern "C" void kernel_launch(void* const* d_in, const int* in_sizes, int n_in,
                              void* d_out, int out_size, void* d_ws, size_t ws_size,
                              hipStream_t stream) {
  const float* x = (const float*)d_in[0];
  const float* Wq = (const float*)d_in[1];
  const float* bq = (const float*)d_in[2];
  const float* Wk = (const float*)d_in[3];
  const float* bk = (const float*)d_in[4];
  const float* Wv = (const float*)d_in[5];
  const float* bv = (const float*)d_in[6];
  const float* Wo = (const float*)d_in[7];
  const float* bo = (const float*)d_in[8];
  const float* gamma = (const float*)d_in[9];
  const float* beta = (const float*)d_in[10];
  float* out = (float*)d_out;

  char* ws = (char*)d_ws;
  unsigned short* wqkvT = (unsigned short*)(ws + 0);          // 6 MB
  unsigned short* woT   = (unsigned short*)(ws + 6291456);    // 2 MB
  unsigned short* h     = (unsigned short*)(ws + 8388608);    // 16 MB
  unsigned short* qb    = (unsigned short*)(ws + 25165824);   // [b,h,s,64] 16 MB
  unsigned short* kb    = (unsigned short*)(ws + 41943040);   // [b,h,s,64] 16 MB
  unsigned short* vT    = (unsigned short*)(ws + 58720256);   // [b,h,64,s] 16 MB
  unsigned short* ao    = (unsigned short*)(ws + 75497472);   // [b,s,1024] 16 MB

  hipLaunchKernelGGL(prep_kernel, dim3(9216), dim3(256), 0, stream,
                     Wq, Wk, Wv, Wo, wqkvT, woT, x, gamma, beta, h);
  hipLaunchKernelGGL(gemm_qkv, dim3(1536), dim3(256), 0, stream,
                     h, wqkvT, bq, bk, bv, qb, kb, vT);
  hipLaunchKernelGGL(attn_kernel, dim3(1024), dim3(256), 0, stream, qb, kb, vT, ao);
  hipLaunchKernelGGL(gemm_out, dim3(512), dim3(256), 0, stream, ao, woT, bo, out);
}

// Round 11
// 269.412 us; speedup vs baseline: 1.1269x; 1.0385x over previous
//
#include <hip/hip_runtime.h>

// ---------------------------------------------------------------------------
// Fused causal MHA: LN -> QKV -> flash attention (S^T trick) -> out proj.
// bf16 MFMA path. B=4, S=2048, D=1024, H=16, hd=64.
// ---------------------------------------------------------------------------

typedef short short8 __attribute__((ext_vector_type(8)));      // 8 bf16 (A/B frag)
typedef float floatx4 __attribute__((ext_vector_type(4)));     // C/D frag
typedef unsigned short ushort4v __attribute__((ext_vector_type(4)));
typedef unsigned int uint2v __attribute__((ext_vector_type(2)));

#define MFMA16(a, b, c) __builtin_amdgcn_mfma_f32_16x16x32_bf16((a), (b), (c), 0, 0, 0)

__device__ __forceinline__ unsigned short f2bf(float f) {
  unsigned int u = __float_as_uint(f);
  u += 0x7FFFu + ((u >> 16) & 1u);
  return (unsigned short)(u >> 16);
}

#if defined(__has_builtin)
#if __has_builtin(__builtin_amdgcn_cvt_pk_bf16_f32)
#define HAVE_PK_BF16 1
#endif
#if __has_builtin(__builtin_amdgcn_exp2f)
#define EXP2(x) __builtin_amdgcn_exp2f(x)
#endif
#if __has_builtin(__builtin_amdgcn_rcpf)
#define RCP(x) __builtin_amdgcn_rcpf(x)
#endif
#endif
#ifndef EXP2
#define EXP2(x) exp2f(x)
#endif
#ifndef RCP
#define RCP(x) (1.0f / (x))
#endif

__device__ __forceinline__ unsigned int pk_bf16(float a, float b) {
#ifdef HAVE_PK_BF16
  typedef __bf16 bf16x2_t __attribute__((ext_vector_type(2)));
  union { bf16x2_t v; unsigned int u; } cvt;
  cvt.v = __builtin_amdgcn_cvt_pk_bf16_f32(a, b);
  return cvt.u;
#else
  return (unsigned int)f2bf(a) | ((unsigned int)f2bf(b) << 16);
#endif
}

// async global -> LDS, 16B per lane. LDS dest = wave-uniform base + lane*16.
__device__ __forceinline__ void async_lds16(const void* g, void* l) {
  __builtin_amdgcn_global_load_lds(
      (const __attribute__((address_space(1))) void*)g,
      (__attribute__((address_space(3))) void*)l, 16, 0, 0);
}

// ---------------------------------------------------------------------------
// Fused prep: blocks [0,1024) transpose weights fp32->bf16 into B^T layout;
// blocks [1024, 9216) do LayerNorm (one block per row).
// ---------------------------------------------------------------------------
__global__ __launch_bounds__(256) void prep_kernel(
    const float* __restrict__ wq, const float* __restrict__ wk,
    const float* __restrict__ wv, const float* __restrict__ wo,
    unsigned short* __restrict__ wqkvT, unsigned short* __restrict__ woT,
    const float* __restrict__ x, const float* __restrict__ gamma,
    const float* __restrict__ beta, unsigned short* __restrict__ h) {
  __shared__ float t[64][65];
  __shared__ float sm[4], qm[4];
  const int id = (int)blockIdx.x;
  const int tid = threadIdx.x;
  if (id < 1024) {
    const int mz = id >> 8, rem = id & 255;
    const int n0 = (rem & 15) * 64, k0 = (rem >> 4) * 64;
    const int r = tid >> 6, c = tid & 63;
    const float* src = (mz == 0) ? wq : (mz == 1) ? wk : (mz == 2) ? wv : wo;
    unsigned short* dst = (mz == 3) ? woT : (wqkvT + (size_t)mz * 1024 * 1024);
#pragma unroll
    for (int i = r; i < 64; i += 4) t[i][c] = src[(size_t)(k0 + i) * 1024 + n0 + c];
    __syncthreads();
#pragma unroll
    for (int i = r; i < 64; i += 4)
      dst[(size_t)(n0 + i) * 1024 + k0 + c] = f2bf(t[c][i]);
    return;
  }
  const int row = id - 1024;
  const float4 xv = ((const float4*)(x + (size_t)row * 1024))[tid];
  float s = xv.x + xv.y + xv.z + xv.w;
  float q = xv.x * xv.x + xv.y * xv.y + xv.z * xv.z + xv.w * xv.w;
#pragma unroll
  for (int off = 32; off > 0; off >>= 1) {
    s += __shfl_xor(s, off, 64);
    q += __shfl_xor(q, off, 64);
  }
  const int wave = tid >> 6, lane = tid & 63;
  if (lane == 0) { sm[wave] = s; qm[wave] = q; }
  __syncthreads();
  s = sm[0] + sm[1] + sm[2] + sm[3];
  q = qm[0] + qm[1] + qm[2] + qm[3];
  const float mean = s * (1.0f / 1024.0f);
  const float var = q * (1.0f / 1024.0f) - mean * mean;
  const float rstd = rsqrtf(var + 1e-5f);
  const float4 g = ((const float4*)gamma)[tid];
  const float4 bb = ((const float4*)beta)[tid];
  ushort4v o;
  o.x = f2bf((xv.x - mean) * rstd * g.x + bb.x);
  o.y = f2bf((xv.y - mean) * rstd * g.y + bb.y);
  o.z = f2bf((xv.z - mean) * rstd * g.z + bb.z);
  o.w = f2bf((xv.w - mean) * rstd * g.w + bb.w);
  ((ushort4v*)(h + (size_t)row * 1024))[tid] = o;
}

// ---------------------------------------------------------------------------
// R11 128x128 GEMM main loop: BK=64 (16 barrier-pairs x 32 MFMA) with
// XOR-swizzled LDS (global chunk ^ (row&7)) -> conflict-free ds_read_b128.
// LDS 32 KB. m0/n0 supplied by caller for swizzling.
// ---------------------------------------------------------------------------
#define GEMM128_MAIN(A_, Bt_, m0_, n0_)                                         \
  __shared__ __align__(16) unsigned short lA[128 * 64];                         \
  __shared__ __align__(16) unsigned short lB[128 * 64];                         \
  const int tid = threadIdx.x;                                                  \
  const int wave = tid >> 6, lane = tid & 63, quad = lane >> 4, l15 = lane & 15;\
  const int wm = wave >> 1, wn = wave & 1;                                      \
  const int m0 = (m0_), n0 = (n0_);                                             \
  const int srow = tid >> 3, schunk = tid & 7;                                  \
  const int swz = l15 & 7;                                                      \
  floatx4 acc[4][4];                                                            \
  _Pragma("unroll") for (int i = 0; i < 4; i++)                                 \
  _Pragma("unroll") for (int j = 0; j < 4; j++)                                 \
      acc[i][j] = (floatx4){0.f, 0.f, 0.f, 0.f};                                \
  for (int kt = 0; kt < 16; kt++) {                                             \
    const int k0 = kt * 64;                                                     \
    __syncthreads();                                                            \
    _Pragma("unroll") for (int j = 0; j < 4; j++) {                             \
      const int row_ = j * 32 + srow;                                           \
      const int gch_ = schunk ^ (row_ & 7);                                     \
      async_lds16(A_ + (size_t)(m0 + row_) * 1024 + k0 + gch_ * 8,              \
                  (char*)lA + j * 4096 + wave * 1024);                          \
      async_lds16(Bt_ + (size_t)(n0 + row_) * 1024 + k0 + gch_ * 8,             \
                  (char*)lB + j * 4096 + wave * 1024);                          \
    }                                                                           \
    __syncthreads();                                                            \
    _Pragma("unroll") for (int kk = 0; kk < 2; kk++) {                          \
      const int ch = (kk * 4 + quad) ^ swz;                                     \
      short8 af[4], bf[4];                                                      \
      _Pragma("unroll") for (int i = 0; i < 4; i++) {                           \
        af[i] = *(const short8*)(lA + (wm * 64 + i * 16 + l15) * 64 + ch * 8);  \
        bf[i] = *(const short8*)(lB + (wn * 64 + i * 16 + l15) * 64 + ch * 8);  \
      }                                                                         \
      _Pragma("unroll") for (int mt = 0; mt < 4; mt++)                          \
      _Pragma("unroll") for (int nt = 0; nt < 4; nt++)                          \
          acc[mt][nt] = MFMA16(af[mt], bf[nt], acc[mt][nt]);                    \
    }                                                                           \
  }

// QKV: M=8192, N=3072. q,k -> [b,h,s,64]; v -> [b,h,64,s].
// q PRE-SCALED by 0.125*log2(e). 1D grid 1536, XCD n-stripe swizzle.
__global__ __launch_bounds__(256) void gemm_qkv(
    const unsigned short* __restrict__ A, const unsigned short* __restrict__ Bt,
    const float* __restrict__ bq, const float* __restrict__ bk,
    const float* __restrict__ bv, unsigned short* __restrict__ qo,
    unsigned short* __restrict__ ko, unsigned short* __restrict__ vT) {
  const int id = (int)blockIdx.x;
  const int xcd = id & 7, rr = id >> 3;
  GEMM128_MAIN(A, Bt, (rr / 3) * 128, (xcd * 3 + (rr % 3)) * 128)
  const int sel = n0 >> 10;  // uniform per block
  const float* bias = (sel == 0) ? bq : (sel == 1) ? bk : bv;
  const float oscale = (sel == 0) ? 0.18033688011112042f : 1.0f;  // 1/8 * log2(e)
#pragma unroll
  for (int nt = 0; nt < 4; nt++) {
    const int n = n0 + wn * 64 + nt * 16 + l15;
    const int nn = n & 1023;
    const float bia = bias[nn];
    const int hidx = nn >> 6, d = nn & 63;
#pragma unroll
    for (int mt = 0; mt < 4; mt++) {
      const int mb = m0 + wm * 64 + mt * 16 + quad * 4;
      const int b = mb >> 11, sdx = mb & 2047;
      if (sel == 2) {
        ushort4v pk;
#pragma unroll
        for (int r = 0; r < 4; r++) pk[r] = f2bf(acc[mt][nt][r] + bia);
        *(ushort4v*)(vT + ((size_t)(b * 16 + hidx) * 64 + d) * 2048 + sdx) = pk;
      } else {
        unsigned short* dst =
            ((sel == 0) ? qo : ko) + ((size_t)(b * 16 + hidx) * 2048 + sdx) * 64 + d;
#pragma unroll
        for (int r = 0; r < 4; r++)
          dst[(size_t)r * 64] = f2bf((acc[mt][nt][r] + bia) * oscale);
      }
    }
  }
}

// Out proj: M=8192, N=1024, fp32 output + bias. 1D grid 512, one n-tile/XCD.
__global__ __launch_bounds__(256) void gemm_out(
    const unsigned short* __restrict__ A, const unsigned short* __restrict__ Bt,
    const float* __restrict__ bo, float* __restrict__ out) {
  const int id = (int)blockIdx.x;
  GEMM128_MAIN(A, Bt, (id >> 3) * 128, (id & 7) * 128)
#pragma unroll
  for (int nt = 0; nt < 4; nt++) {
    const int n = n0 + wn * 64 + nt * 16 + l15;
    const float bia = bo[n];
#pragma unroll
    for (int mt = 0; mt < 4; mt++) {
      const int m = m0 + wm * 64 + mt * 16 + quad * 4;
#pragma unroll
      for (int r = 0; r < 4; r++) out[(size_t)(m + r) * 1024 + n] = acc[mt][nt][r] + bia;
    }
  }
}

// ---------------------------------------------------------------------------
// Flash attention, causal, S^T formulation (R10 config, frozen):
//  - native v_exp_f32 / v_rcp_f32 (no OCML expansion)
//  - V in LDS; MERGED PASSES (one sweep serves q-tiles 31-qx and qx)
//  - NO-MAX softmax (log2-domain scores), denominator via ones-MFMA
//  - XCD-locality decode; LDS 40 KB; launch_bounds(256,4).
// ---------------------------------------------------------------------------
__global__ __launch_bounds__(256, 4) void attn_kernel(
    const unsigned short* __restrict__ q, const unsigned short* __restrict__ k,
    const unsigned short* __restrict__ vT, unsigned short* __restrict__ ao) {
  __shared__ __align__(16) unsigned short lK[2][64 * 64];  // 16 KB dbuf
  __shared__ __align__(16) unsigned short lV[2][64 * 64];  // 16 KB dbuf
  __shared__ __align__(16) unsigned short lP[4][16 * 64];  // 8 KB (swizzled)
  const int tid = threadIdx.x;
  const int wave = tid >> 6, lane = tid & 63, quad = lane >> 4, l15 = lane & 15;
  const int id = (int)blockIdx.x;
  const int bh = (id & 7) * 8 + ((id >> 3) & 7);
  const int qx = id >> 6;  // 0..15
  const int b = bh >> 4, hh = bh & 15;
  const int qtA = 31 - qx, qtB = qx;  // big & small q-tiles, qtB < qtA
  const int q0wA = qtA * 64 + wave * 16, q0wB = qtB * 64 + wave * 16;
  const int ntiles = qtA + 1;

  const unsigned short* qb = q + (size_t)bh * 2048 * 64;
  const unsigned short* kb = k + (size_t)bh * 2048 * 64;
  const unsigned short* vb = vT + (size_t)bh * 64 * 2048;
  unsigned short* pw = &lP[wave][0];

  const int srow = tid >> 3, schunk = tid & 7;  // staging row / 16B chunk

  const short8 ones8 = {0x3F80, 0x3F80, 0x3F80, 0x3F80,
                        0x3F80, 0x3F80, 0x3F80, 0x3F80};

  const int sw = l15 & 7;
  const int ph0 = (0 * 4 + quad) ^ sw, ph1 = (1 * 4 + quad) ^ sw;

#define STAGE_TILE(src_, rstride_, cbase_, dst_)                                 \
  _Pragma("unroll") for (int j = 0; j < 2; j++) {                                \
    const int row_ = j * 32 + srow;                                              \
    const int gch_ = schunk ^ (row_ & 7);                                        \
    async_lds16(src_ + (size_t)row_ * (rstride_) + (cbase_) + gch_ * 8,          \
                (char*)(dst_) + j * 4096 + wave * 1024);                         \
  }

  short8 qfA[2], qfB[2];
#pragma unroll
  for (int hf = 0; hf < 2; hf++) {
    qfA[hf] = *(const short8*)(qb + (size_t)(q0wA + l15) * 64 + hf * 32 + quad * 8);
    qfB[hf] = *(const short8*)(qb + (size_t)(q0wB + l15) * 64 + hf * 32 + quad * 8);
  }

  floatx4 oA[4], oB[4];
#pragma unroll
  for (int nt = 0; nt < 4; nt++) {
    oA[nt] = (floatx4){0.f, 0.f, 0.f, 0.f};
    oB[nt] = (floatx4){0.f, 0.f, 0.f, 0.f};
  }
  floatx4 laccA = {0.f, 0.f, 0.f, 0.f}, laccB = {0.f, 0.f, 0.f, 0.f};

  STAGE_TILE(kb, 64, 0, &lK[0][0])
  STAGE_TILE(vb, 2048, 0, &lV[0][0])
  int kbase = 0;
  for (int t = 0; t < ntiles; t++, kbase += 64) {
    __syncthreads();
    if (t + 1 < ntiles) {
      const int nb = (t + 1) & 1;
      STAGE_TILE(kb, 64, (size_t)(kbase + 64) * 64, &lK[nb][0])
      STAGE_TILE(vb, 2048, (size_t)(kbase + 64), &lV[nb][0])
    }
    const unsigned short* lKc = &lK[t & 1][0];
    const unsigned short* lVc = &lV[t & 1][0];
    const bool dual = (t <= qtB);  // block-uniform

    floatx4 scA[4], scB[4];
#pragma unroll
    for (int nt = 0; nt < 4; nt++) {
      scA[nt] = (floatx4){0.f, 0.f, 0.f, 0.f};
      scB[nt] = (floatx4){0.f, 0.f, 0.f, 0.f};
      const short8 kf0 = *(const short8*)(lKc + (nt * 16 + l15) * 64 + ph0 * 8);
      const short8 kf1 = *(const short8*)(lKc + (nt * 16 + l15) * 64 + ph1 * 8);
      scA[nt] = MFMA16(kf0, qfA[0], scA[nt]);
      scA[nt] = MFMA16(kf1, qfA[1], scA[nt]);
      if (dual) {
        scB[nt] = MFMA16(kf0, qfB[0], scB[nt]);
        scB[nt] = MFMA16(kf1, qfB[1], scB[nt]);
      }
    }

    {
      const bool needmask = (kbase + 63 > q0wA);
      const int qg = q0wA + l15;
#pragma unroll
      for (int nt = 0; nt < 4; nt++) {
        float p0 = EXP2(scA[nt][0]), p1 = EXP2(scA[nt][1]);
        float p2 = EXP2(scA[nt][2]), p3 = EXP2(scA[nt][3]);
        if (needmask) {
          const int kk = kbase + nt * 16 + quad * 4;
          if (kk + 0 > qg) p0 = 0.f;
          if (kk + 1 > qg) p1 = 0.f;
          if (kk + 2 > qg) p2 = 0.f;
          if (kk + 3 > qg) p3 = 0.f;
        }
        uint2v pk2;
        pk2.x = pk_bf16(p0, p1);
        pk2.y = pk_bf16(p2, p3);
        const int phys = (nt * 2 + (quad >> 1)) ^ sw;
        *(uint2v*)(pw + l15 * 64 + phys * 8 + (quad & 1) * 4) = pk2;
      }
    }
    asm volatile("s_waitcnt lgkmcnt(0)" ::: "memory");
    short8 pfA0 = *(const short8*)(pw + l15 * 64 + ph0 * 8);
    short8 pfA1 = *(const short8*)(pw + l15 * 64 + ph1 * 8);

    short8 pfB0, pfB1;
    if (dual) {
      const bool needmask = (kbase + 63 > q0wB);
      const int qg = q0wB + l15;
#pragma unroll
      for (int nt = 0; nt < 4; nt++) {
        float p0 = EXP2(scB[nt][0]), p1 = EXP2(scB[nt][1]);
        float p2 = EXP2(scB[nt][2]), p3 = EXP2(scB[nt][3]);
        if (needmask) {
          const int kk = kbase + nt * 16 + quad * 4;
          if (kk + 0 > qg) p0 = 0.f;
          if (kk + 1 > qg) p1 = 0.f;
          if (kk + 2 > qg) p2 = 0.f;
          if (kk + 3 > qg) p3 = 0.f;
        }
        uint2v pk2;
        pk2.x = pk_bf16(p0, p1);
        pk2.y = pk_bf16(p2, p3);
        const int phys = (nt * 2 + (quad >> 1)) ^ sw;
        *(uint2v*)(pw + l15 * 64 + phys * 8 + (quad & 1) * 4) = pk2;
      }
      asm volatile("s_waitcnt lgkmcnt(0)" ::: "memory");
      pfB0 = *(const short8*)(pw + l15 * 64 + ph0 * 8);
      pfB1 = *(const short8*)(pw + l15 * 64 + ph1 * 8);
    }

#pragma unroll
    for (int hf = 0; hf < 2; hf++) {
      const short8 pfA = hf ? pfA1 : pfA0;
      laccA = MFMA16(ones8, pfA, laccA);
      if (dual) laccB = MFMA16(ones8, hf ? pfB1 : pfB0, laccB);
      const int ph = hf ? ph1 : ph0;
#pragma unroll
      for (int nt = 0; nt < 4; nt++) {
        const short8 vf = *(const short8*)(lVc + (nt * 16 + l15) * 64 + ph * 8);
        oA[nt] = MFMA16(vf, pfA, oA[nt]);
        if (dual) oB[nt] = MFMA16(vf, hf ? pfB1 : pfB0, oB[nt]);
      }
    }
  }

  {
    const float linv = RCP(laccA[0]);
    unsigned short* dst = ao + ((size_t)b * 2048 + q0wA + l15) * 1024 + hh * 64;
#pragma unroll
    for (int nt = 0; nt < 4; nt++) {
      uint2v pk2;
      pk2.x = pk_bf16(oA[nt][0] * linv, oA[nt][1] * linv);
      pk2.y = pk_bf16(oA[nt][2] * linv, oA[nt][3] * linv);
      *(uint2v*)(dst + nt * 16 + quad * 4) = pk2;
    }
  }
  {
    const float linv = RCP(laccB[0]);
    unsigned short* dst = ao + ((size_t)b * 2048 + q0wB + l15) * 1024 + hh * 64;
#pragma unroll
    for (int nt = 0; nt < 4; nt++) {
      uint2v pk2;
      pk2.x = pk_bf16(oB[nt][0] * linv, oB[nt][1] * linv);
      pk2.y = pk_bf16(oB[nt][2] * linv, oB[nt][3] * linv);
      *(uint2v*)(dst + nt * 16 + quad * 4) = pk2;
    }
  }
#undef STAGE_TILE
}

// ---------------------------------------------------------------------------
extern "C" void kernel_launch(void* const* d_in, const int* in_sizes, int n_in,
                              void* d_out, int out_size, void* d_ws, size_t ws_size,
                              hipStream_t stream) {
  const float* x = (const float*)d_in[0];
  const float* Wq = (const float*)d_in[1];
  const float* bq = (const float*)d_in[2];
  const float* Wk = (const float*)d_in[3];
  const float* bk = (const float*)d_in[4];
  const float* Wv = (const float*)d_in[5];
  const float* bv = (const float*)d_in[6];
  const float* Wo = (const float*)d_in[7];
  const float* bo = (const float*)d_in[8];
  const float* gamma = (const float*)d_in[9];
  const float* beta = (const float*)d_in[10];
  float* out = (float*)d_out;

  char* ws = (char*)d_ws;
  unsigned short* wqkvT = (unsigned short*)(ws + 0);          // 6 MB
  unsigned short* woT   = (unsigned short*)(ws + 6291456);    // 2 MB
  unsigned short* h     = (unsigned short*)(ws + 8388608);    // 16 MB
  unsigned short* qb    = (unsigned short*)(ws + 25165824);   // [b,h,s,64] 16 MB
  unsigned short* kb    = (unsigned short*)(ws + 41943040);   // [b,h,s,64] 16 MB
  unsigned short* vT    = (unsigned short*)(ws + 58720256);   // [b,h,64,s] 16 MB
  unsigned short* ao    = (unsigned short*)(ws + 75497472);   // [b,s,1024] 16 MB

  hipLaunchKernelGGL(prep_kernel, dim3(9216), dim3(256), 0, stream,
                     Wq, Wk, Wv, Wo, wqkvT, woT, x, gamma, beta, h);
  hipLaunchKernelGGL(gemm_qkv, dim3(1536), dim3(256), 0, stream,
                     h, wqkvT, bq, bk, bv, qb, kb, vT);
  hipLaunchKernelGGL(attn_kernel, dim3(1024), dim3(256), 0, stream, qb, kb, vT, ao);
  hipLaunchKernelGGL(gemm_out, dim3(512), dim3(256), 0, stream, ao, woT, bo, out);
}